// Round 1
// baseline (344.558 us; speedup 1.0000x reference)
//
#include <hip/hip_runtime.h>

// RaggedSelectThreshold: keep rows with xs > 0.5, stably compact pl rows to the
// front of an [N,F] buffer (zero-padded), emit new row splits and scatter idxs.
// All outputs written as float32 values (harness reads d_out as one f32 blob).
//
// d_out layout (floats): [N*F newfeat][B+1 new_rs][N scatter_idxs]
// d_ws layout (ints):    [N ranks][1024 blk_counts][1024 blk_off][1 n_sel]

#define THRESH 0.5f
#define RPB 1024   // rows per block in pass A (4 chunks of 256 threads)

// Pass A: per-row encoded prefix: (count of selected rows in [blk_start, i) << 1) | mask
__global__ void k_count(const float* __restrict__ xs, int N,
                        int* __restrict__ ranks, int* __restrict__ blk_counts) {
    __shared__ int wc[4][4];                     // [chunk][wave]
    const int tid  = threadIdx.x;
    const int lane = tid & 63, wave = tid >> 6;
    const int base = blockIdx.x * RPB;
    int running = 0;
    for (int c = 0; c < 4; ++c) {
        int i = base + c * 256 + tid;
        int m = (i < N) && (xs[i] > THRESH);
        unsigned long long bal = __ballot(m);
        if (lane == 0) wc[c][wave] = __popcll(bal);
        __syncthreads();
        int waveoff = 0, tot = 0;
        for (int w = 0; w < 4; ++w) { int v = wc[c][w]; if (w < wave) waveoff += v; tot += v; }
        int pre = running + waveoff + (int)__popcll(bal & ((1ull << lane) - 1ull));
        if (i < N) ranks[i] = (pre << 1) | m;
        running += tot;
    }
    if (tid == 0) blk_counts[blockIdx.x] = running;
}

// Pass B: scan block counts (nblocks <= 1024), write offsets + n_sel + new_rs.
__global__ void k_scan(const int* __restrict__ blk_counts, int nblocks,
                       const int* __restrict__ ranks,
                       const int* __restrict__ rs, int nrs, int N,
                       int* __restrict__ blk_off, int* __restrict__ nsel_out,
                       float* __restrict__ out_rs) {
    __shared__ int s[1024];
    __shared__ int s_total;
    const int t = threadIdx.x;
    int v = (t < nblocks) ? blk_counts[t] : 0;
    s[t] = v;
    __syncthreads();
    // Hillis-Steele inclusive scan over 1024 entries
    for (int d = 1; d < 1024; d <<= 1) {
        int add = (t >= d) ? s[t - d] : 0;
        __syncthreads();
        s[t] += add;
        __syncthreads();
    }
    int excl = s[t] - v;
    if (t < nblocks) blk_off[t] = excl;
    if (t == 1023) s_total = s[t];
    __syncthreads();                 // also makes blk_off global writes visible in-block
    int n_sel = s_total;
    if (t == 0) nsel_out[0] = n_sel;
    if (t < nrs) {
        int j = rs[t];
        int val;
        if (j >= N)      val = n_sel;
        else if (j <= 0) val = 0;
        else             val = blk_off[j >> 10] + (ranks[j] >> 1);
        out_rs[t] = (float)val;      // int32 output written as numeric f32 (exact, <2^24)
    }
}

// Pass C: scatter indices. Selected row i -> slot rank; tail slots get N.
__global__ void k_scatter(const int* __restrict__ ranks, const int* __restrict__ blk_off,
                          const int* __restrict__ nsel, int N,
                          float* __restrict__ out_sc) {
    int i = blockIdx.x * blockDim.x + threadIdx.x;
    if (i >= N) return;
    int ns = nsel[0];
    int e  = ranks[i];
    if (e & 1) {
        int r = blk_off[i >> 10] + (e >> 1);
        out_sc[r] = (float)i;
    }
    if (i >= ns) out_sc[i] = (float)N;   // disjoint from rank slots ([0,ns))
}

// Pass D: gather payload rows through scatter idxs; coalesced float4 writes.
// 16 lanes per row (F=64 -> 16 float4).
__global__ void k_gather(const float* __restrict__ out_sc, const float4* __restrict__ pl4,
                         int N, float4* __restrict__ outf4) {
    int tid = blockIdx.x * blockDim.x + threadIdx.x;
    int r = tid >> 4;
    int c = tid & 15;
    if (r >= N) return;
    int idx = (int)out_sc[r];            // same-address broadcast within 16 lanes
    float4 v = make_float4(0.f, 0.f, 0.f, 0.f);
    if (idx < N) v = pl4[(size_t)idx * 16 + c];
    outf4[(size_t)r * 16 + c] = v;
}

extern "C" void kernel_launch(void* const* d_in, const int* in_sizes, int n_in,
                              void* d_out, int out_size, void* d_ws, size_t ws_size,
                              hipStream_t stream) {
    const float* xs = (const float*)d_in[0];
    const float* pl = (const float*)d_in[1];
    const int*   rs = (const int*)d_in[2];
    const int N   = in_sizes[0];        // 800000
    const int F   = in_sizes[1] / N;    // 64 (kernel D assumes 64)
    const int nrs = in_sizes[2];        // B+1 = 9

    float* out      = (float*)d_out;
    float* out_feat = out;
    float* out_rs   = out + (size_t)N * F;
    float* out_sc   = out_rs + nrs;

    int* ranks      = (int*)d_ws;
    int* blk_counts = ranks + N;
    int* blk_off    = blk_counts + 1024;
    int* nsel       = blk_off + 1024;

    const int nblocks = (N + RPB - 1) / RPB;   // 782 (must be <= 1024)

    k_count  <<<nblocks,           256,  0, stream>>>(xs, N, ranks, blk_counts);
    k_scan   <<<1,                 1024, 0, stream>>>(blk_counts, nblocks, ranks, rs, nrs, N,
                                                      blk_off, nsel, out_rs);
    k_scatter<<<(N + 255) / 256,   256,  0, stream>>>(ranks, blk_off, nsel, N, out_sc);
    k_gather <<<(N * (F / 4) + 255) / 256, 256, 0, stream>>>(out_sc, (const float4*)pl,
                                                             N, (float4*)out_feat);
}